// Round 1
// baseline (620.284 us; speedup 1.0000x reference)
//
#include <hip/hip_runtime.h>
#include <hip/hip_bf16.h>
#include <math.h>

// GCN 2-layer: agg[d] = isq[d] * (sum_{e: dst=d} Hs[src[e]] + Hs[d]),
// Hs = (H @ W) * isq[row].  CSR built on device each call (deterministic work).

// ---------------- graph prep ----------------

__global__ void k_count(const int* __restrict__ dstA, int* __restrict__ deg, int E) {
    int i = blockIdx.x * blockDim.x + threadIdx.x;
    if (i < E) atomicAdd(&deg[dstA[i]], 1);
}

__global__ __launch_bounds__(256) void k_bsum(const int* __restrict__ deg,
                                              int* __restrict__ bsums, int n) {
    int i = blockIdx.x * 256 + threadIdx.x;
    int v = (i < n) ? deg[i] : 0;
    #pragma unroll
    for (int o = 32; o; o >>= 1) v += __shfl_down(v, o, 64);
    __shared__ int wsum[4];
    if ((threadIdx.x & 63) == 0) wsum[threadIdx.x >> 6] = v;
    __syncthreads();
    if (threadIdx.x == 0) bsums[blockIdx.x] = wsum[0] + wsum[1] + wsum[2] + wsum[3];
}

// exclusive scan of up to 1024 block sums, single block
__global__ __launch_bounds__(1024) void k_scan_b(int* __restrict__ bsums, int nb) {
    __shared__ int s[1024];
    int t = threadIdx.x;
    s[t] = (t < nb) ? bsums[t] : 0;
    __syncthreads();
    for (int o = 1; o < 1024; o <<= 1) {
        int add = (t >= o) ? s[t - o] : 0;
        __syncthreads();
        s[t] += add;
        __syncthreads();
    }
    if (t < nb) bsums[t] = (t == 0) ? 0 : s[t - 1];
}

__global__ __launch_bounds__(256) void k_scan_local(const int* __restrict__ deg,
                                                    const int* __restrict__ bsums,
                                                    int* __restrict__ offs,
                                                    int* __restrict__ cursor, int n) {
    __shared__ int s[256];
    int t = threadIdx.x;
    int i = blockIdx.x * 256 + t;
    int v = (i < n) ? deg[i] : 0;
    s[t] = v;
    __syncthreads();
    for (int o = 1; o < 256; o <<= 1) {
        int add = (t >= o) ? s[t - o] : 0;
        __syncthreads();
        s[t] += add;
        __syncthreads();
    }
    int excl = (t == 0) ? 0 : s[t - 1];
    int off = bsums[blockIdx.x] + excl;
    if (i < n) { offs[i] = off; cursor[i] = off; }
    if (i == n - 1) offs[n] = off + v;
}

__global__ void k_isq(const int* __restrict__ deg, float* __restrict__ isq, int n) {
    int i = blockIdx.x * blockDim.x + threadIdx.x;
    if (i < n) isq[i] = rsqrtf((float)(deg[i] + 1));   // +1 self loop
}

__global__ void k_fill(const int* __restrict__ srcA, const int* __restrict__ dstA,
                       int* __restrict__ cursor, int* __restrict__ csr, int E) {
    int e = blockIdx.x * blockDim.x + threadIdx.x;
    if (e < E) {
        int d = dstA[e];
        int p = atomicAdd(&cursor[d], 1);
        csr[p] = srcA[e];
    }
}

// ---------------- GEMM1: Hs1 = (x @ W1) * isq[row], 128x128 ----------------
// block = 256 threads (4 waves), 32 rows/block, full 128 cols.
// W staged in two 64-row halves (32KB) + x tile (16KB) => 48KB LDS static.

__global__ __launch_bounds__(256) void k_gemm1(const float* __restrict__ x,
                                               const float* __restrict__ W,
                                               const float* __restrict__ isq,
                                               float* __restrict__ out, int n) {
    __shared__ float Wl[64 * 128];   // 32KB: half of W (k rows)
    __shared__ float xs[32][128];    // 16KB
    const int t = threadIdx.x;
    const int row0 = blockIdx.x * 32;

    {   // stage x tile: 1024 float4
        const float4* xv = (const float4*)(x + (size_t)row0 * 128);
        float4* xsv = (float4*)&xs[0][0];
        #pragma unroll
        for (int i = 0; i < 4; ++i) xsv[t + 256 * i] = xv[t + 256 * i];
    }

    const int lane = t & 63;
    const int wave = t >> 6;
    const int half = lane >> 5;
    const int c0 = (lane & 31) * 4;          // 4 consecutive cols per lane
    const int rbase = wave * 8 + half * 4;   // 4 rows per lane

    float4 acc[4] = {};

    for (int kh = 0; kh < 2; ++kh) {
        __syncthreads();
        {   // stage W rows kh*64 .. kh*64+63 : 2048 float4
            const float4* Wv = (const float4*)(W + (size_t)kh * 64 * 128);
            float4* Wlv = (float4*)Wl;
            #pragma unroll
            for (int i = 0; i < 8; ++i) Wlv[t + 256 * i] = Wv[t + 256 * i];
        }
        __syncthreads();
        #pragma unroll 4
        for (int k = 0; k < 64; ++k) {
            float4 w4 = *(const float4*)&Wl[k * 128 + c0];
            const int kk = kh * 64 + k;
            #pragma unroll
            for (int r = 0; r < 4; ++r) {
                float xr = xs[rbase + r][kk];
                acc[r].x = fmaf(xr, w4.x, acc[r].x);
                acc[r].y = fmaf(xr, w4.y, acc[r].y);
                acc[r].z = fmaf(xr, w4.z, acc[r].z);
                acc[r].w = fmaf(xr, w4.w, acc[r].w);
            }
        }
    }
    #pragma unroll
    for (int r = 0; r < 4; ++r) {
        const int row = row0 + rbase + r;      // N % 32 == 0, no guard needed
        const float s = isq[row];
        float4 v = acc[r];
        v.x *= s; v.y *= s; v.z *= s; v.w *= s;
        *(float4*)&out[(size_t)row * 128 + c0] = v;
    }
}

// ---------------- agg layer 1: one wave per node, 128 feats (float2/lane) ----

__global__ __launch_bounds__(256) void k_agg1(const float* __restrict__ Hs,
                                              const int* __restrict__ csr,
                                              const int* __restrict__ offs,
                                              const float* __restrict__ isq,
                                              const float* __restrict__ b1,
                                              float* __restrict__ out, int n) {
    int wid = (int)((blockIdx.x * (size_t)blockDim.x + threadIdx.x) >> 6);
    int lane = threadIdx.x & 63;
    if (wid >= n) return;
    const int d = wid;
    const int e0 = offs[d], e1 = offs[d + 1];
    float2 acc = *(const float2*)&Hs[(size_t)d * 128 + lane * 2];  // self loop
    for (int e = e0; e < e1; ++e) {
        int s = csr[e];
        float2 v = *(const float2*)&Hs[(size_t)s * 128 + lane * 2];
        acc.x += v.x; acc.y += v.y;
    }
    const float sc = isq[d];
    float2 bb = *(const float2*)&b1[lane * 2];
    float2 o;
    o.x = fmaxf(fmaf(acc.x, sc, bb.x), 0.f);
    o.y = fmaxf(fmaf(acc.y, sc, bb.y), 0.f);
    *(float2*)&out[(size_t)d * 128 + lane * 2] = o;
}

// ---------------- GEMM2: Hs2 = (H1 @ W2) * isq[row], 128x40 ----------------
// block = 320 threads (5 waves): col = t%40, rows t/40 and t/40+8; 16 rows/blk.

__global__ __launch_bounds__(320) void k_gemm2(const float* __restrict__ h,
                                               const float* __restrict__ W,
                                               const float* __restrict__ isq,
                                               float* __restrict__ out, int n) {
    __shared__ float Wl[128 * 40];   // 20KB
    __shared__ float hs[16][128];    // 8KB
    const int t = threadIdx.x;
    const int row0 = blockIdx.x * 16;
    {   // stage W2: 1280 float4
        const float4* Wv = (const float4*)W;
        float4* Wlv = (float4*)Wl;
        #pragma unroll
        for (int i = 0; i < 4; ++i) Wlv[t + 320 * i] = Wv[t + 320 * i];
    }
    {   // stage h tile: 512 float4
        const float4* hv = (const float4*)(h + (size_t)row0 * 128);
        float4* hsv = (float4*)&hs[0][0];
        for (int idx = t; idx < 512; idx += 320) hsv[idx] = hv[idx];
    }
    __syncthreads();
    const int col = t % 40;
    const int rsub = t / 40;   // 0..7
    float acc0 = 0.f, acc1 = 0.f;
    #pragma unroll 4
    for (int k = 0; k < 128; ++k) {
        float w = Wl[k * 40 + col];
        acc0 = fmaf(hs[rsub][k], w, acc0);
        acc1 = fmaf(hs[rsub + 8][k], w, acc1);
    }
    const int r0 = row0 + rsub, r1 = r0 + 8;   // N % 16 == 0
    out[(size_t)r0 * 40 + col] = acc0 * isq[r0];
    out[(size_t)r1 * 40 + col] = acc1 * isq[r1];
}

// ---------------- agg layer 2 + bias + log_softmax (C=40) ----------------

__global__ __launch_bounds__(256) void k_agg2(const float* __restrict__ Hs,
                                              const int* __restrict__ csr,
                                              const int* __restrict__ offs,
                                              const float* __restrict__ isq,
                                              const float* __restrict__ b2,
                                              float* __restrict__ out, int n) {
    int wid = (int)((blockIdx.x * (size_t)blockDim.x + threadIdx.x) >> 6);
    int lane = threadIdx.x & 63;
    if (wid >= n) return;
    const int d = wid;
    const int e0 = offs[d], e1 = offs[d + 1];
    float acc = 0.f;
    if (lane < 40) acc = Hs[(size_t)d * 40 + lane];   // self loop
    for (int e = e0; e < e1; ++e) {
        int s = csr[e];
        if (lane < 40) acc += Hs[(size_t)s * 40 + lane];
    }
    float v = -INFINITY;
    if (lane < 40) v = fmaf(acc, isq[d], b2[lane]);
    // wave max
    float m = v;
    #pragma unroll
    for (int o = 32; o; o >>= 1) m = fmaxf(m, __shfl_xor(m, o, 64));
    float ex = (lane < 40) ? expf(v - m) : 0.f;
    float ssum = ex;
    #pragma unroll
    for (int o = 32; o; o >>= 1) ssum += __shfl_xor(ssum, o, 64);
    float lse = m + logf(ssum);
    if (lane < 40) out[(size_t)d * 40 + lane] = v - lse;
}

// ---------------- launch ----------------

extern "C" void kernel_launch(void* const* d_in, const int* in_sizes, int n_in,
                              void* d_out, int out_size, void* d_ws, size_t ws_size,
                              hipStream_t stream) {
    const float* x  = (const float*)d_in[0];
    const int*   ei = (const int*)d_in[1];
    const float* W1 = (const float*)d_in[2];
    const float* b1 = (const float*)d_in[3];
    const float* W2 = (const float*)d_in[4];
    const float* b2 = (const float*)d_in[5];
    float* out = (float*)d_out;

    const int N = in_sizes[0] / 128;
    const int E = in_sizes[1] / 2;
    const int* srcA = ei;
    const int* dstA = ei + E;

    char* ws = (char*)d_ws;
    size_t off = 0;
    auto alloc = [&](size_t bytes) -> void* {
        void* p = ws + off;
        off += (bytes + 255) & ~(size_t)255;
        return p;
    };
    int*   deg    = (int*)alloc((size_t)N * 4);
    int*   offs   = (int*)alloc((size_t)(N + 1) * 4);
    int*   cursor = (int*)alloc((size_t)N * 4);
    int*   bsums  = (int*)alloc(4096);
    float* isq    = (float*)alloc((size_t)N * 4);
    int*   csr    = (int*)alloc((size_t)E * 4);
    float* Hs1    = (float*)alloc((size_t)N * 128 * 4);
    float* H1     = (float*)alloc((size_t)N * 128 * 4);
    float* Hs2    = Hs1;   // Hs1 dead after k_agg1 -> reuse for layer-2 transform

    const int nb = (N + 255) / 256;

    hipMemsetAsync(deg, 0, (size_t)N * 4, stream);
    k_count<<<(E + 255) / 256, 256, 0, stream>>>(dstA, deg, E);
    k_bsum<<<nb, 256, 0, stream>>>(deg, bsums, N);
    k_scan_b<<<1, 1024, 0, stream>>>(bsums, nb);
    k_scan_local<<<nb, 256, 0, stream>>>(deg, bsums, offs, cursor, N);
    k_isq<<<nb, 256, 0, stream>>>(deg, isq, N);
    k_fill<<<(E + 255) / 256, 256, 0, stream>>>(srcA, dstA, cursor, csr, E);

    k_gemm1<<<(N + 31) / 32, 256, 0, stream>>>(x, W1, isq, Hs1, N);
    k_agg1<<<(N + 3) / 4, 256, 0, stream>>>(Hs1, csr, offs, isq, b1, H1, N);
    k_gemm2<<<(N + 15) / 16, 320, 0, stream>>>(H1, W2, isq, Hs2, N);
    k_agg2<<<(N + 3) / 4, 256, 0, stream>>>(Hs2, csr, offs, isq, b2, out, N);
}

// Round 2
// 379.671 us; speedup vs baseline: 1.6337x; 1.6337x over previous
//
#include <hip/hip_runtime.h>
#include <hip/hip_bf16.h>
#include <math.h>

typedef __bf16 bf16x8 __attribute__((ext_vector_type(8)));
typedef float  f32x4  __attribute__((ext_vector_type(4)));

__device__ __forceinline__ unsigned short f2b(float f) {
    union { float f; unsigned u; } v; v.f = f;
    unsigned r = v.u + 0x7fffu + ((v.u >> 16) & 1u);   // RNE
    return (unsigned short)(r >> 16);
}
__device__ __forceinline__ float b2f_lo(unsigned u) {
    union { unsigned u; float f; } v; v.u = u << 16; return v.f;
}
__device__ __forceinline__ float b2f_hi(unsigned u) {
    union { unsigned u; float f; } v; v.u = u & 0xffff0000u; return v.f;
}

// ---------------- graph prep ----------------

__global__ void k_count(const int* __restrict__ dstA, int* __restrict__ deg, int E) {
    int i = blockIdx.x * blockDim.x + threadIdx.x;
    if (i < E) atomicAdd(&deg[dstA[i]], 1);
}

__global__ __launch_bounds__(256) void k_bsum(const int* __restrict__ deg,
                                              int* __restrict__ bsums, int n) {
    int i = blockIdx.x * 256 + threadIdx.x;
    int v = (i < n) ? deg[i] : 0;
    #pragma unroll
    for (int o = 32; o; o >>= 1) v += __shfl_down(v, o, 64);
    __shared__ int wsum[4];
    if ((threadIdx.x & 63) == 0) wsum[threadIdx.x >> 6] = v;
    __syncthreads();
    if (threadIdx.x == 0) bsums[blockIdx.x] = wsum[0] + wsum[1] + wsum[2] + wsum[3];
}

__global__ __launch_bounds__(1024) void k_scan_b(int* __restrict__ bsums, int nb) {
    __shared__ int s[1024];
    int t = threadIdx.x;
    s[t] = (t < nb) ? bsums[t] : 0;
    __syncthreads();
    for (int o = 1; o < 1024; o <<= 1) {
        int add = (t >= o) ? s[t - o] : 0;
        __syncthreads();
        s[t] += add;
        __syncthreads();
    }
    if (t < nb) bsums[t] = (t == 0) ? 0 : s[t - 1];
}

__global__ __launch_bounds__(256) void k_scan_local(const int* __restrict__ deg,
                                                    const int* __restrict__ bsums,
                                                    int* __restrict__ offs,
                                                    int* __restrict__ cursor, int n) {
    __shared__ int s[256];
    int t = threadIdx.x;
    int i = blockIdx.x * 256 + t;
    int v = (i < n) ? deg[i] : 0;
    s[t] = v;
    __syncthreads();
    for (int o = 1; o < 256; o <<= 1) {
        int add = (t >= o) ? s[t - o] : 0;
        __syncthreads();
        s[t] += add;
        __syncthreads();
    }
    int excl = (t == 0) ? 0 : s[t - 1];
    int off = bsums[blockIdx.x] + excl;
    if (i < n) { offs[i] = off; cursor[i] = off; }
    if (i == n - 1) offs[n] = off + v;
}

__global__ void k_isq(const int* __restrict__ deg, float* __restrict__ isq, int n) {
    int i = blockIdx.x * blockDim.x + threadIdx.x;
    if (i < n) isq[i] = rsqrtf((float)(deg[i] + 1));
}

__global__ void k_fill(const int* __restrict__ srcA, const int* __restrict__ dstA,
                       int* __restrict__ cursor, int* __restrict__ csr, int E) {
    int e = blockIdx.x * blockDim.x + threadIdx.x;
    if (e < E) {
        int d = dstA[e];
        int p = atomicAdd(&cursor[d], 1);
        csr[p] = srcA[e];
    }
}

// W1t[c][k] = bf16(W1[k][c]);  W2t[c][k] = bf16(W2[k][c]) zero-padded to 48 cols
__global__ void k_prepw(const float* __restrict__ W1, const float* __restrict__ W2,
                        __bf16* __restrict__ W1t, __bf16* __restrict__ W2t) {
    int idx = blockIdx.x * 256 + threadIdx.x;
    if (idx < 128 * 128) {
        int k = idx >> 7, c = idx & 127;
        W1t[c * 128 + k] = (__bf16)W1[idx];
    }
    if (idx < 48 * 128) {
        int c = idx >> 7, k = idx & 127;
        W2t[idx] = (c < 40) ? (__bf16)W2[k * 40 + c] : (__bf16)0.f;
    }
}

// ---------------- GEMM1 (MFMA): Hs1 = bf16((x @ W1) * isq[row]) ----------------
// wave-per-16-rows, no LDS. A-frag: lane = row(l&15), k=(l>>4)*8+j.
// B-frag: lane = col(l&15), k=(l>>4)*8+j (from W1t transposed layout).
// C: col=l&15, row=(l>>4)*4+reg  [verified layout]

__global__ __launch_bounds__(256) void k_gemm1(const float* __restrict__ x,
                                               const __bf16* __restrict__ W1t,
                                               const float* __restrict__ isq,
                                               unsigned short* __restrict__ out, int n) {
    const int lane = threadIdx.x & 63;
    const int wid  = blockIdx.x * 4 + (threadIdx.x >> 6);
    const int r0 = wid * 16;
    if (r0 >= n) return;
    const int mr = lane & 15;
    const int kg = lane >> 4;

    bf16x8 af[4];
    const float* xrow = x + (size_t)(r0 + mr) * 128 + kg * 8;
    #pragma unroll
    for (int s = 0; s < 4; ++s) {
        f32x4 u0 = *(const f32x4*)(xrow + s * 32);
        f32x4 u1 = *(const f32x4*)(xrow + s * 32 + 4);
        bf16x8 a;
        a[0] = (__bf16)u0[0]; a[1] = (__bf16)u0[1]; a[2] = (__bf16)u0[2]; a[3] = (__bf16)u0[3];
        a[4] = (__bf16)u1[0]; a[5] = (__bf16)u1[1]; a[6] = (__bf16)u1[2]; a[7] = (__bf16)u1[3];
        af[s] = a;
    }
    float sc[4];
    #pragma unroll
    for (int r = 0; r < 4; ++r) sc[r] = isq[r0 + kg * 4 + r];

    #pragma unroll
    for (int nt = 0; nt < 8; ++nt) {
        const __bf16* wp = W1t + (size_t)(nt * 16 + mr) * 128 + kg * 8;
        f32x4 acc = {0.f, 0.f, 0.f, 0.f};
        #pragma unroll
        for (int s = 0; s < 4; ++s) {
            bf16x8 bfr = *(const bf16x8*)(wp + s * 32);
            acc = __builtin_amdgcn_mfma_f32_16x16x32_bf16(af[s], bfr, acc, 0, 0, 0);
        }
        #pragma unroll
        for (int r = 0; r < 4; ++r) {
            int row = r0 + kg * 4 + r;
            out[(size_t)row * 128 + nt * 16 + mr] = f2b(acc[r] * sc[r]);
        }
    }
}

// ---------------- agg1: H1 = bf16(relu(isq*(sum srcs + self) + b1)) ----------------
// wave per node; 4 edges/iter (16 lanes x 16B = 256B bf16 row each), masked fma,
// index prefetch + unroll 2 for multiple gathers in flight.

__global__ __launch_bounds__(256) void k_agg1(const unsigned short* __restrict__ Hs,
                                              const int* __restrict__ csr,
                                              const int* __restrict__ offs,
                                              const float* __restrict__ isq,
                                              const float* __restrict__ b1,
                                              unsigned short* __restrict__ out, int n) {
    int wid = (int)((blockIdx.x * (size_t)blockDim.x + threadIdx.x) >> 6);
    if (wid >= n) return;
    const int lane = threadIdx.x & 63;
    const int g = lane >> 4, p = lane & 15;
    const int d = wid;
    const int e0 = offs[d], e1 = offs[d + 1];

    float acc[8] = {0.f, 0.f, 0.f, 0.f, 0.f, 0.f, 0.f, 0.f};
    if (g == 0) {  // self loop
        int4 w = *(const int4*)(Hs + (size_t)d * 128 + p * 8);
        acc[0] = b2f_lo((unsigned)w.x); acc[1] = b2f_hi((unsigned)w.x);
        acc[2] = b2f_lo((unsigned)w.y); acc[3] = b2f_hi((unsigned)w.y);
        acc[4] = b2f_lo((unsigned)w.z); acc[5] = b2f_hi((unsigned)w.z);
        acc[6] = b2f_lo((unsigned)w.w); acc[7] = b2f_hi((unsigned)w.w);
    }

    const int cnt = e1 - e0;
    const int nit = (cnt + 3) >> 2;
    int e = e0 + g;
    int idx;
    {
        bool v = e < e1;
        int t = csr[v ? e : 0];
        idx = v ? t : -1;
    }
    #pragma unroll 2
    for (int it = 0; it < nit; ++it) {
        int cur = idx;
        e += 4;
        bool nv = e < e1;
        int t = csr[nv ? e : 0];
        idx = nv ? t : -1;
        int srow = (cur >= 0) ? cur : 0;
        int4 w = *(const int4*)(Hs + (size_t)srow * 128 + p * 8);
        float m = (cur >= 0) ? 1.f : 0.f;
        acc[0] = fmaf(m, b2f_lo((unsigned)w.x), acc[0]);
        acc[1] = fmaf(m, b2f_hi((unsigned)w.x), acc[1]);
        acc[2] = fmaf(m, b2f_lo((unsigned)w.y), acc[2]);
        acc[3] = fmaf(m, b2f_hi((unsigned)w.y), acc[3]);
        acc[4] = fmaf(m, b2f_lo((unsigned)w.z), acc[4]);
        acc[5] = fmaf(m, b2f_hi((unsigned)w.z), acc[5]);
        acc[6] = fmaf(m, b2f_lo((unsigned)w.w), acc[6]);
        acc[7] = fmaf(m, b2f_hi((unsigned)w.w), acc[7]);
    }
    #pragma unroll
    for (int j = 0; j < 8; ++j) {
        acc[j] += __shfl_xor(acc[j], 16, 64);
        acc[j] += __shfl_xor(acc[j], 32, 64);
    }
    if (g == 0) {
        const float s = isq[d];
        f32x4 bb0 = *(const f32x4*)(b1 + p * 8);
        f32x4 bb1 = *(const f32x4*)(b1 + p * 8 + 4);
        unsigned short o[8];
        o[0] = f2b(fmaxf(fmaf(acc[0], s, bb0[0]), 0.f));
        o[1] = f2b(fmaxf(fmaf(acc[1], s, bb0[1]), 0.f));
        o[2] = f2b(fmaxf(fmaf(acc[2], s, bb0[2]), 0.f));
        o[3] = f2b(fmaxf(fmaf(acc[3], s, bb0[3]), 0.f));
        o[4] = f2b(fmaxf(fmaf(acc[4], s, bb1[0]), 0.f));
        o[5] = f2b(fmaxf(fmaf(acc[5], s, bb1[1]), 0.f));
        o[6] = f2b(fmaxf(fmaf(acc[6], s, bb1[2]), 0.f));
        o[7] = f2b(fmaxf(fmaf(acc[7], s, bb1[3]), 0.f));
        int4 r;
        r.x = (int)((unsigned)o[0] | ((unsigned)o[1] << 16));
        r.y = (int)((unsigned)o[2] | ((unsigned)o[3] << 16));
        r.z = (int)((unsigned)o[4] | ((unsigned)o[5] << 16));
        r.w = (int)((unsigned)o[6] | ((unsigned)o[7] << 16));
        *(int4*)(out + (size_t)d * 128 + p * 8) = r;
    }
}

// ---------------- GEMM2 (MFMA): Hs2 = (H1 @ W2) * isq[row], fp32 out ----------------

__global__ __launch_bounds__(256) void k_gemm2(const __bf16* __restrict__ h,
                                               const __bf16* __restrict__ W2t,
                                               const float* __restrict__ isq,
                                               float* __restrict__ out, int n) {
    const int lane = threadIdx.x & 63;
    const int wid  = blockIdx.x * 4 + (threadIdx.x >> 6);
    const int r0 = wid * 16;
    if (r0 >= n) return;
    const int mr = lane & 15;
    const int kg = lane >> 4;

    bf16x8 af[4];
    const __bf16* hrow = h + (size_t)(r0 + mr) * 128 + kg * 8;
    #pragma unroll
    for (int s = 0; s < 4; ++s) af[s] = *(const bf16x8*)(hrow + s * 32);
    float sc[4];
    #pragma unroll
    for (int r = 0; r < 4; ++r) sc[r] = isq[r0 + kg * 4 + r];

    #pragma unroll
    for (int nt = 0; nt < 3; ++nt) {
        const __bf16* wp = W2t + (size_t)(nt * 16 + mr) * 128 + kg * 8;
        f32x4 acc = {0.f, 0.f, 0.f, 0.f};
        #pragma unroll
        for (int s = 0; s < 4; ++s) {
            bf16x8 bfr = *(const bf16x8*)(wp + s * 32);
            acc = __builtin_amdgcn_mfma_f32_16x16x32_bf16(af[s], bfr, acc, 0, 0, 0);
        }
        int col = nt * 16 + mr;
        if (col < 40) {
            #pragma unroll
            for (int r = 0; r < 4; ++r) {
                int row = r0 + kg * 4 + r;
                out[(size_t)row * 40 + col] = acc[r] * sc[r];
            }
        }
    }
}

// ---------------- agg2 + bias + log_softmax (C=40, fp32) ----------------
// 4 edges/iter; 10 lanes/group load float4 (160B row).

__global__ __launch_bounds__(256) void k_agg2(const float* __restrict__ Hs,
                                              const int* __restrict__ csr,
                                              const int* __restrict__ offs,
                                              const float* __restrict__ isq,
                                              const float* __restrict__ b2,
                                              float* __restrict__ out, int n) {
    int wid = (int)((blockIdx.x * (size_t)blockDim.x + threadIdx.x) >> 6);
    if (wid >= n) return;
    const int lane = threadIdx.x & 63;
    const int g = lane >> 4, p = lane & 15;
    const bool act = p < 10;
    const int pc = act ? p : 9;
    const int d = wid;
    const int e0 = offs[d], e1 = offs[d + 1];

    f32x4 acc = {0.f, 0.f, 0.f, 0.f};
    {
        f32x4 sv = *(const f32x4*)(Hs + (size_t)d * 40 + pc * 4);
        if (g == 0 && act) acc = sv;
    }
    const int cnt = e1 - e0;
    const int nit = (cnt + 3) >> 2;
    int e = e0 + g;
    int idx;
    {
        bool v = e < e1;
        int t = csr[v ? e : 0];
        idx = v ? t : -1;
    }
    #pragma unroll 2
    for (int it = 0; it < nit; ++it) {
        int cur = idx;
        e += 4;
        bool nv = e < e1;
        int t = csr[nv ? e : 0];
        idx = nv ? t : -1;
        int srow = (cur >= 0) ? cur : 0;
        f32x4 w = *(const f32x4*)(Hs + (size_t)srow * 40 + pc * 4);
        float m = (cur >= 0 && act) ? 1.f : 0.f;
        acc[0] = fmaf(m, w[0], acc[0]);
        acc[1] = fmaf(m, w[1], acc[1]);
        acc[2] = fmaf(m, w[2], acc[2]);
        acc[3] = fmaf(m, w[3], acc[3]);
    }
    #pragma unroll
    for (int j = 0; j < 4; ++j) {
        acc[j] += __shfl_xor(acc[j], 16, 64);
        acc[j] += __shfl_xor(acc[j], 32, 64);
    }
    const float s = isq[d];
    f32x4 bb = *(const f32x4*)(b2 + pc * 4);
    f32x4 v4;
    v4[0] = fmaf(acc[0], s, bb[0]);
    v4[1] = fmaf(acc[1], s, bb[1]);
    v4[2] = fmaf(acc[2], s, bb[2]);
    v4[3] = fmaf(acc[3], s, bb[3]);

    float lm = act ? fmaxf(fmaxf(v4[0], v4[1]), fmaxf(v4[2], v4[3])) : -INFINITY;
    #pragma unroll
    for (int o = 8; o; o >>= 1) lm = fmaxf(lm, __shfl_xor(lm, o, 64));
    float es = act ? (expf(v4[0] - lm) + expf(v4[1] - lm) + expf(v4[2] - lm) + expf(v4[3] - lm)) : 0.f;
    #pragma unroll
    for (int o = 8; o; o >>= 1) es += __shfl_xor(es, o, 64);
    float lse = lm + logf(es);
    if (g == 0 && act) {
        f32x4 r;
        r[0] = v4[0] - lse; r[1] = v4[1] - lse; r[2] = v4[2] - lse; r[3] = v4[3] - lse;
        *(f32x4*)(out + (size_t)d * 40 + p * 4) = r;
    }
}

// ---------------- launch ----------------

extern "C" void kernel_launch(void* const* d_in, const int* in_sizes, int n_in,
                              void* d_out, int out_size, void* d_ws, size_t ws_size,
                              hipStream_t stream) {
    const float* x  = (const float*)d_in[0];
    const int*   ei = (const int*)d_in[1];
    const float* W1 = (const float*)d_in[2];
    const float* b1 = (const float*)d_in[3];
    const float* W2 = (const float*)d_in[4];
    const float* b2 = (const float*)d_in[5];
    float* out = (float*)d_out;

    const int N = in_sizes[0] / 128;
    const int E = in_sizes[1] / 2;
    const int* srcA = ei;
    const int* dstA = ei + E;

    char* ws = (char*)d_ws;
    size_t off = 0;
    auto alloc = [&](size_t bytes) -> void* {
        void* p = ws + off;
        off += (bytes + 255) & ~(size_t)255;
        return p;
    };
    int*    deg    = (int*)alloc((size_t)N * 4);
    int*    offs   = (int*)alloc((size_t)(N + 1) * 4);
    int*    cursor = (int*)alloc((size_t)N * 4);
    int*    bsums  = (int*)alloc(4096);
    float*  isq    = (float*)alloc((size_t)N * 4);
    int*    csr    = (int*)alloc((size_t)E * 4);
    __bf16* W1t    = (__bf16*)alloc(128 * 128 * 2);
    __bf16* W2t    = (__bf16*)alloc(48 * 128 * 2);
    unsigned short* Hs1 = (unsigned short*)alloc((size_t)N * 128 * 2);
    unsigned short* H1  = (unsigned short*)alloc((size_t)N * 128 * 2);
    float*  Hs2   = (float*)alloc((size_t)N * 40 * 4);

    const int nb = (N + 255) / 256;

    hipMemsetAsync(deg, 0, (size_t)N * 4, stream);
    k_count<<<(E + 255) / 256, 256, 0, stream>>>(dstA, deg, E);
    k_bsum<<<nb, 256, 0, stream>>>(deg, bsums, N);
    k_scan_b<<<1, 1024, 0, stream>>>(bsums, nb);
    k_scan_local<<<nb, 256, 0, stream>>>(deg, bsums, offs, cursor, N);
    k_isq<<<nb, 256, 0, stream>>>(deg, isq, N);
    k_fill<<<(E + 255) / 256, 256, 0, stream>>>(srcA, dstA, cursor, csr, E);
    k_prepw<<<64, 256, 0, stream>>>(W1, W2, W1t, W2t);

    const int nwav = (N + 15) / 16;
    k_gemm1<<<(nwav + 3) / 4, 256, 0, stream>>>(x, W1t, isq, Hs1, N);
    k_agg1<<<(N + 3) / 4, 256, 0, stream>>>(Hs1, csr, offs, isq, b1, H1, N);
    k_gemm2<<<(nwav + 3) / 4, 256, 0, stream>>>((const __bf16*)H1, W2t, isq, Hs2, N);
    k_agg2<<<(N + 3) / 4, 256, 0, stream>>>(Hs2, csr, offs, isq, b2, out, N);
}

// Round 3
// 253.454 us; speedup vs baseline: 2.4473x; 1.4980x over previous
//
#include <hip/hip_runtime.h>
#include <hip/hip_bf16.h>
#include <math.h>

typedef __bf16 bf16x8 __attribute__((ext_vector_type(8)));
typedef float  f32x4  __attribute__((ext_vector_type(4)));

__device__ __forceinline__ unsigned short f2b(float f) {
    union { float f; unsigned u; } v; v.f = f;
    unsigned r = v.u + 0x7fffu + ((v.u >> 16) & 1u);   // RNE
    return (unsigned short)(r >> 16);
}
__device__ __forceinline__ float b2f_lo(unsigned u) {
    union { unsigned u; float f; } v; v.u = u << 16; return v.f;
}
__device__ __forceinline__ float b2f_hi(unsigned u) {
    union { unsigned u; float f; } v; v.u = u & 0xffff0000u; return v.f;
}

// ================= CSR build: two-level counting sort (LDS atomics only) ====
// bucket = dst >> 9 (512 nodes/bucket). NB_SC edge-chunks (blocks) per pass.

#define NB_SC 128

// per-(bucket,block) histogram, bucket-major layout hist[buk*NB_SC + blk]
__global__ __launch_bounds__(256) void k_hist(const int* __restrict__ dstA,
                                              int* __restrict__ hist_g,
                                              int E, int nbuk, int chunk) {
    __shared__ int h[256];
    const int t = threadIdx.x, b = blockIdx.x;
    h[t] = 0;
    __syncthreads();
    const int e0 = b * chunk, e1 = min(E, e0 + chunk);
    for (int e = e0 + t; e < e1; e += 256) atomicAdd(&h[dstA[e] >> 9], 1);
    __syncthreads();
    if (t < nbuk) hist_g[t * NB_SC + b] = h[t];
}

// in-place exclusive scan of M ints (M <= 1024*per)
__global__ __launch_bounds__(1024) void k_scan_hist(int* __restrict__ hist, int M) {
    __shared__ int ts[1024];
    const int t = threadIdx.x;
    const int per = (M + 1023) >> 10;
    const int s0 = t * per, s1 = min(M, s0 + per);
    int sum = 0;
    for (int i = s0; i < s1; ++i) sum += hist[i];
    ts[t] = sum;
    __syncthreads();
    for (int o = 1; o < 1024; o <<= 1) {
        int a = (t >= o) ? ts[t - o] : 0;
        __syncthreads();
        ts[t] += a;
        __syncthreads();
    }
    int run = (t == 0) ? 0 : ts[t - 1];
    for (int i = s0; i < s1; ++i) { int v = hist[i]; hist[i] = run; run += v; }
}

// scatter edges into dst-bucket-partitioned array, packed (src<<9)|dstLocal
__global__ __launch_bounds__(256) void k_scatter(const int* __restrict__ srcA,
                                                 const int* __restrict__ dstA,
                                                 const int* __restrict__ base,
                                                 unsigned* __restrict__ part,
                                                 int E, int nbuk, int chunk) {
    __shared__ int cur[256];
    const int t = threadIdx.x, b = blockIdx.x;
    if (t < nbuk) cur[t] = base[t * NB_SC + b];
    __syncthreads();
    const int e0 = b * chunk, e1 = min(E, e0 + chunk);
    for (int e = e0 + t; e < e1; e += 256) {
        int d = dstA[e];
        int s = srcA[e];
        int buk = d >> 9;
        int p = atomicAdd(&cur[buk], 1);
        part[p] = ((unsigned)s << 9) | (unsigned)(d & 511);
    }
}

// per-bucket local CSR: LDS count -> LDS scan -> fill; also offs/isq
__global__ __launch_bounds__(512) void k_lcsr(const unsigned* __restrict__ part,
                                              const int* __restrict__ base,
                                              int* __restrict__ csr,
                                              int* __restrict__ offs,
                                              float* __restrict__ isq,
                                              int E, int N, int nbuk) {
    __shared__ int deg[512];
    __shared__ int sc[512];
    __shared__ int cur[512];
    const int t = threadIdx.x, buk = blockIdx.x;
    const int n0 = buk << 9;
    const int nn = min(512, N - n0);
    const int e0 = base[buk * NB_SC];
    const int e1 = (buk + 1 < nbuk) ? base[(buk + 1) * NB_SC] : E;
    deg[t] = 0;
    __syncthreads();
    for (int e = e0 + t; e < e1; e += 512) atomicAdd(&deg[part[e] & 511], 1);
    __syncthreads();
    int v = deg[t];
    sc[t] = v;
    __syncthreads();
    for (int o = 1; o < 512; o <<= 1) {
        int a = (t >= o) ? sc[t - o] : 0;
        __syncthreads();
        sc[t] += a;
        __syncthreads();
    }
    const int excl = (t == 0) ? 0 : sc[t - 1];
    cur[t] = e0 + excl;
    if (t < nn) {
        offs[n0 + t] = e0 + excl;
        isq[n0 + t] = rsqrtf((float)(deg[t] + 1));   // +1 self loop
    }
    if (buk == nbuk - 1 && t == 0) offs[N] = E;
    __syncthreads();
    for (int e = e0 + t; e < e1; e += 512) {
        unsigned w = part[e];
        int dl = (int)(w & 511u);
        int p = atomicAdd(&cur[dl], 1);
        csr[p] = (int)(w >> 9);
    }
}

// W1t[c][k] = bf16(W1[k][c]);  W2t[c][k] = bf16(W2[k][c]) zero-padded to 48 cols
__global__ void k_prepw(const float* __restrict__ W1, const float* __restrict__ W2,
                        __bf16* __restrict__ W1t, __bf16* __restrict__ W2t) {
    int idx = blockIdx.x * 256 + threadIdx.x;
    if (idx < 128 * 128) {
        int k = idx >> 7, c = idx & 127;
        W1t[c * 128 + k] = (__bf16)W1[idx];
    }
    if (idx < 48 * 128) {
        int c = idx >> 7, k = idx & 127;
        W2t[idx] = (c < 40) ? (__bf16)W2[k * 40 + c] : (__bf16)0.f;
    }
}

// ---------------- GEMM1 (MFMA): Hs1 = bf16((x @ W1) * isq[row]) ----------------

__global__ __launch_bounds__(256) void k_gemm1(const float* __restrict__ x,
                                               const __bf16* __restrict__ W1t,
                                               const float* __restrict__ isq,
                                               unsigned short* __restrict__ out, int n) {
    const int lane = threadIdx.x & 63;
    const int wid  = blockIdx.x * 4 + (threadIdx.x >> 6);
    const int r0 = wid * 16;
    if (r0 >= n) return;
    const int mr = lane & 15;
    const int kg = lane >> 4;

    bf16x8 af[4];
    const float* xrow = x + (size_t)(r0 + mr) * 128 + kg * 8;
    #pragma unroll
    for (int s = 0; s < 4; ++s) {
        f32x4 u0 = *(const f32x4*)(xrow + s * 32);
        f32x4 u1 = *(const f32x4*)(xrow + s * 32 + 4);
        bf16x8 a;
        a[0] = (__bf16)u0[0]; a[1] = (__bf16)u0[1]; a[2] = (__bf16)u0[2]; a[3] = (__bf16)u0[3];
        a[4] = (__bf16)u1[0]; a[5] = (__bf16)u1[1]; a[6] = (__bf16)u1[2]; a[7] = (__bf16)u1[3];
        af[s] = a;
    }
    float sc[4];
    #pragma unroll
    for (int r = 0; r < 4; ++r) sc[r] = isq[r0 + kg * 4 + r];

    #pragma unroll
    for (int nt = 0; nt < 8; ++nt) {
        const __bf16* wp = W1t + (size_t)(nt * 16 + mr) * 128 + kg * 8;
        f32x4 acc = {0.f, 0.f, 0.f, 0.f};
        #pragma unroll
        for (int s = 0; s < 4; ++s) {
            bf16x8 bfr = *(const bf16x8*)(wp + s * 32);
            acc = __builtin_amdgcn_mfma_f32_16x16x32_bf16(af[s], bfr, acc, 0, 0, 0);
        }
        #pragma unroll
        for (int r = 0; r < 4; ++r) {
            int row = r0 + kg * 4 + r;
            out[(size_t)row * 128 + nt * 16 + mr] = f2b(acc[r] * sc[r]);
        }
    }
}

// ---------------- agg1: H1 = bf16(relu(isq*(sum srcs + self) + b1)) ----------------

__global__ __launch_bounds__(256) void k_agg1(const unsigned short* __restrict__ Hs,
                                              const int* __restrict__ csr,
                                              const int* __restrict__ offs,
                                              const float* __restrict__ isq,
                                              const float* __restrict__ b1,
                                              unsigned short* __restrict__ out, int n) {
    int wid = (int)((blockIdx.x * (size_t)blockDim.x + threadIdx.x) >> 6);
    if (wid >= n) return;
    const int lane = threadIdx.x & 63;
    const int g = lane >> 4, p = lane & 15;
    const int d = wid;
    const int e0 = offs[d], e1 = offs[d + 1];

    float acc[8] = {0.f, 0.f, 0.f, 0.f, 0.f, 0.f, 0.f, 0.f};
    if (g == 0) {  // self loop
        int4 w = *(const int4*)(Hs + (size_t)d * 128 + p * 8);
        acc[0] = b2f_lo((unsigned)w.x); acc[1] = b2f_hi((unsigned)w.x);
        acc[2] = b2f_lo((unsigned)w.y); acc[3] = b2f_hi((unsigned)w.y);
        acc[4] = b2f_lo((unsigned)w.z); acc[5] = b2f_hi((unsigned)w.z);
        acc[6] = b2f_lo((unsigned)w.w); acc[7] = b2f_hi((unsigned)w.w);
    }

    const int cnt = e1 - e0;
    const int nit = (cnt + 3) >> 2;
    int e = e0 + g;
    int idx;
    {
        bool v = e < e1;
        int t = csr[v ? e : 0];
        idx = v ? t : -1;
    }
    #pragma unroll 2
    for (int it = 0; it < nit; ++it) {
        int cur = idx;
        e += 4;
        bool nv = e < e1;
        int t = csr[nv ? e : 0];
        idx = nv ? t : -1;
        int srow = (cur >= 0) ? cur : 0;
        int4 w = *(const int4*)(Hs + (size_t)srow * 128 + p * 8);
        float m = (cur >= 0) ? 1.f : 0.f;
        acc[0] = fmaf(m, b2f_lo((unsigned)w.x), acc[0]);
        acc[1] = fmaf(m, b2f_hi((unsigned)w.x), acc[1]);
        acc[2] = fmaf(m, b2f_lo((unsigned)w.y), acc[2]);
        acc[3] = fmaf(m, b2f_hi((unsigned)w.y), acc[3]);
        acc[4] = fmaf(m, b2f_lo((unsigned)w.z), acc[4]);
        acc[5] = fmaf(m, b2f_hi((unsigned)w.z), acc[5]);
        acc[6] = fmaf(m, b2f_lo((unsigned)w.w), acc[6]);
        acc[7] = fmaf(m, b2f_hi((unsigned)w.w), acc[7]);
    }
    #pragma unroll
    for (int j = 0; j < 8; ++j) {
        acc[j] += __shfl_xor(acc[j], 16, 64);
        acc[j] += __shfl_xor(acc[j], 32, 64);
    }
    if (g == 0) {
        const float s = isq[d];
        f32x4 bb0 = *(const f32x4*)(b1 + p * 8);
        f32x4 bb1 = *(const f32x4*)(b1 + p * 8 + 4);
        unsigned short o[8];
        o[0] = f2b(fmaxf(fmaf(acc[0], s, bb0[0]), 0.f));
        o[1] = f2b(fmaxf(fmaf(acc[1], s, bb0[1]), 0.f));
        o[2] = f2b(fmaxf(fmaf(acc[2], s, bb0[2]), 0.f));
        o[3] = f2b(fmaxf(fmaf(acc[3], s, bb0[3]), 0.f));
        o[4] = f2b(fmaxf(fmaf(acc[4], s, bb1[0]), 0.f));
        o[5] = f2b(fmaxf(fmaf(acc[5], s, bb1[1]), 0.f));
        o[6] = f2b(fmaxf(fmaf(acc[6], s, bb1[2]), 0.f));
        o[7] = f2b(fmaxf(fmaf(acc[7], s, bb1[3]), 0.f));
        int4 r;
        r.x = (int)((unsigned)o[0] | ((unsigned)o[1] << 16));
        r.y = (int)((unsigned)o[2] | ((unsigned)o[3] << 16));
        r.z = (int)((unsigned)o[4] | ((unsigned)o[5] << 16));
        r.w = (int)((unsigned)o[6] | ((unsigned)o[7] << 16));
        *(int4*)(out + (size_t)d * 128 + p * 8) = r;
    }
}

// ---------------- GEMM2 (MFMA): Hs2 = bf16((H1 @ W2) * isq[row]) ----------------

__global__ __launch_bounds__(256) void k_gemm2(const __bf16* __restrict__ h,
                                               const __bf16* __restrict__ W2t,
                                               const float* __restrict__ isq,
                                               unsigned short* __restrict__ out, int n) {
    const int lane = threadIdx.x & 63;
    const int wid  = blockIdx.x * 4 + (threadIdx.x >> 6);
    const int r0 = wid * 16;
    if (r0 >= n) return;
    const int mr = lane & 15;
    const int kg = lane >> 4;

    bf16x8 af[4];
    const __bf16* hrow = h + (size_t)(r0 + mr) * 128 + kg * 8;
    #pragma unroll
    for (int s = 0; s < 4; ++s) af[s] = *(const bf16x8*)(hrow + s * 32);
    float sc[4];
    #pragma unroll
    for (int r = 0; r < 4; ++r) sc[r] = isq[r0 + kg * 4 + r];

    #pragma unroll
    for (int nt = 0; nt < 3; ++nt) {
        const __bf16* wp = W2t + (size_t)(nt * 16 + mr) * 128 + kg * 8;
        f32x4 acc = {0.f, 0.f, 0.f, 0.f};
        #pragma unroll
        for (int s = 0; s < 4; ++s) {
            bf16x8 bfr = *(const bf16x8*)(wp + s * 32);
            acc = __builtin_amdgcn_mfma_f32_16x16x32_bf16(af[s], bfr, acc, 0, 0, 0);
        }
        int col = nt * 16 + mr;
        if (col < 40) {
            #pragma unroll
            for (int r = 0; r < 4; ++r) {
                int row = r0 + kg * 4 + r;
                out[(size_t)row * 40 + col] = f2b(acc[r] * sc[r]);
            }
        }
    }
}

// ---------------- agg2 + bias + log_softmax (C=40, bf16 gather) ----------------
// row = 40 bf16 = 80B = 10 lanes x int2 (4 ch each)

__global__ __launch_bounds__(256) void k_agg2(const unsigned short* __restrict__ Hs,
                                              const int* __restrict__ csr,
                                              const int* __restrict__ offs,
                                              const float* __restrict__ isq,
                                              const float* __restrict__ b2,
                                              float* __restrict__ out, int n) {
    int wid = (int)((blockIdx.x * (size_t)blockDim.x + threadIdx.x) >> 6);
    if (wid >= n) return;
    const int lane = threadIdx.x & 63;
    const int g = lane >> 4, p = lane & 15;
    const bool act = p < 10;
    const int pc = act ? p : 9;
    const int d = wid;
    const int e0 = offs[d], e1 = offs[d + 1];

    float acc[4] = {0.f, 0.f, 0.f, 0.f};
    {
        int2 w = *(const int2*)(Hs + (size_t)d * 40 + pc * 4);
        if (g == 0 && act) {
            acc[0] = b2f_lo((unsigned)w.x); acc[1] = b2f_hi((unsigned)w.x);
            acc[2] = b2f_lo((unsigned)w.y); acc[3] = b2f_hi((unsigned)w.y);
        }
    }
    const int cnt = e1 - e0;
    const int nit = (cnt + 3) >> 2;
    int e = e0 + g;
    int idx;
    {
        bool v = e < e1;
        int t = csr[v ? e : 0];
        idx = v ? t : -1;
    }
    #pragma unroll 2
    for (int it = 0; it < nit; ++it) {
        int cur = idx;
        e += 4;
        bool nv = e < e1;
        int t = csr[nv ? e : 0];
        idx = nv ? t : -1;
        int srow = (cur >= 0) ? cur : 0;
        int2 w = *(const int2*)(Hs + (size_t)srow * 40 + pc * 4);
        float m = (cur >= 0 && act) ? 1.f : 0.f;
        acc[0] = fmaf(m, b2f_lo((unsigned)w.x), acc[0]);
        acc[1] = fmaf(m, b2f_hi((unsigned)w.x), acc[1]);
        acc[2] = fmaf(m, b2f_lo((unsigned)w.y), acc[2]);
        acc[3] = fmaf(m, b2f_hi((unsigned)w.y), acc[3]);
    }
    #pragma unroll
    for (int j = 0; j < 4; ++j) {
        acc[j] += __shfl_xor(acc[j], 16, 64);
        acc[j] += __shfl_xor(acc[j], 32, 64);
    }
    const float s = isq[d];
    f32x4 bb = *(const f32x4*)(b2 + pc * 4);
    f32x4 v4;
    v4[0] = fmaf(acc[0], s, bb[0]);
    v4[1] = fmaf(acc[1], s, bb[1]);
    v4[2] = fmaf(acc[2], s, bb[2]);
    v4[3] = fmaf(acc[3], s, bb[3]);

    float lm = act ? fmaxf(fmaxf(v4[0], v4[1]), fmaxf(v4[2], v4[3])) : -INFINITY;
    #pragma unroll
    for (int o = 8; o; o >>= 1) lm = fmaxf(lm, __shfl_xor(lm, o, 64));
    float es = act ? (expf(v4[0] - lm) + expf(v4[1] - lm) + expf(v4[2] - lm) + expf(v4[3] - lm)) : 0.f;
    #pragma unroll
    for (int o = 8; o; o >>= 1) es += __shfl_xor(es, o, 64);
    float lse = lm + logf(es);
    if (g == 0 && act) {
        f32x4 r;
        r[0] = v4[0] - lse; r[1] = v4[1] - lse; r[2] = v4[2] - lse; r[3] = v4[3] - lse;
        *(f32x4*)(out + (size_t)d * 40 + p * 4) = r;
    }
}

// ---------------- launch ----------------

extern "C" void kernel_launch(void* const* d_in, const int* in_sizes, int n_in,
                              void* d_out, int out_size, void* d_ws, size_t ws_size,
                              hipStream_t stream) {
    const float* x  = (const float*)d_in[0];
    const int*   ei = (const int*)d_in[1];
    const float* W1 = (const float*)d_in[2];
    const float* b1 = (const float*)d_in[3];
    const float* W2 = (const float*)d_in[4];
    const float* b2 = (const float*)d_in[5];
    float* out = (float*)d_out;

    const int N = in_sizes[0] / 128;
    const int E = in_sizes[1] / 2;
    const int* srcA = ei;
    const int* dstA = ei + E;
    const int nbuk = (N + 511) >> 9;              // <= 256 for N <= 131072
    const int chunk = (E + NB_SC - 1) / NB_SC;

    char* ws = (char*)d_ws;
    size_t off = 0;
    auto alloc = [&](size_t bytes) -> void* {
        void* p = ws + off;
        off += (bytes + 255) & ~(size_t)255;
        return p;
    };
    int*      hist = (int*)alloc((size_t)nbuk * NB_SC * 4);
    unsigned* part = (unsigned*)alloc((size_t)E * 4);
    int*      offs = (int*)alloc((size_t)(N + 1) * 4);
    float*    isq  = (float*)alloc((size_t)N * 4);
    int*      csr  = (int*)alloc((size_t)E * 4);
    __bf16*   W1t  = (__bf16*)alloc(128 * 128 * 2);
    __bf16*   W2t  = (__bf16*)alloc(48 * 128 * 2);
    unsigned short* Hs1 = (unsigned short*)alloc((size_t)N * 128 * 2);
    unsigned short* H1  = (unsigned short*)alloc((size_t)N * 128 * 2);
    unsigned short* Hs2 = (unsigned short*)alloc((size_t)N * 40 * 2);

    k_prepw<<<64, 256, 0, stream>>>(W1, W2, W1t, W2t);
    k_hist<<<NB_SC, 256, 0, stream>>>(dstA, hist, E, nbuk, chunk);
    k_scan_hist<<<1, 1024, 0, stream>>>(hist, nbuk * NB_SC);
    k_scatter<<<NB_SC, 256, 0, stream>>>(srcA, dstA, hist, part, E, nbuk, chunk);
    k_lcsr<<<nbuk, 512, 0, stream>>>(part, hist, csr, offs, isq, E, N, nbuk);

    const int nwav = (N + 15) / 16;
    k_gemm1<<<(nwav + 3) / 4, 256, 0, stream>>>(x, W1t, isq, Hs1, N);
    k_agg1<<<(N + 3) / 4, 256, 0, stream>>>(Hs1, csr, offs, isq, b1, H1, N);
    k_gemm2<<<(nwav + 3) / 4, 256, 0, stream>>>((const __bf16*)H1, W2t, isq, Hs2, N);
    k_agg2<<<(N + 3) / 4, 256, 0, stream>>>(Hs2, csr, offs, isq, b2, out, N);
}